// Round 1
// baseline (434.369 us; speedup 1.0000x reference)
//
#include <hip/hip_runtime.h>

#define LIMG 4
#define CIN 256
#define HH 128
#define WW 256
#define HW 32768          // HH*WW
#define LHW 131072        // LIMG*HW
#define CD 128
#define KP 256
#define CAP 8192
#define NSP 2
#define CPER (CIN/NSP)    // 128

// ---------------- init ----------------
__global__ void k_init(int* __restrict__ cnt) {
  int t = threadIdx.x;
  if (t < LIMG) cnt[t] = 0;
}

// ---------------- transpose convD weights: wT[(c*9+tap)*CD + d] ----------------
__global__ void k_wtrans(const float* __restrict__ wD, float* __restrict__ wT) {
  int i = blockIdx.x * 256 + threadIdx.x;
  if (i >= CD * CIN * 9) return;
  int d = i & (CD - 1);
  int j = i >> 7;                    // c*9+tap
  wT[i] = wD[d * (CIN * 9) + j];
}

// ---------------- channel-reduced score planes ----------------
__global__ __launch_bounds__(256) void k_chanred(const float* __restrict__ feats,
                                                 const float* __restrict__ wS,
                                                 float* __restrict__ g) {
  int gp   = (blockIdx.x & 511) * 256 + threadIdx.x;  // 0..131071
  int half = blockIdx.x >> 9;                         // 0..NSP-1
  int l  = gp >> 15;
  int pi = gp & (HW - 1);
  const float* f = feats + (size_t)(l * CIN + half * CPER) * HW + pi;
  const float* w = wS + half * CPER * 9;
  float a0=0,a1=0,a2=0,a3=0,a4=0,a5=0,a6=0,a7=0,a8=0;
  #pragma unroll 4
  for (int c = 0; c < CPER; ++c) {
    float v = f[(size_t)c * HW];
    const float* wc = w + c * 9;
    a0 = fmaf(wc[0], v, a0); a1 = fmaf(wc[1], v, a1); a2 = fmaf(wc[2], v, a2);
    a3 = fmaf(wc[3], v, a3); a4 = fmaf(wc[4], v, a4); a5 = fmaf(wc[5], v, a5);
    a6 = fmaf(wc[6], v, a6); a7 = fmaf(wc[7], v, a7); a8 = fmaf(wc[8], v, a8);
  }
  float* go = g + (size_t)(half * 9) * LHW + gp;
  go[0*(size_t)LHW]=a0; go[1*(size_t)LHW]=a1; go[2*(size_t)LHW]=a2;
  go[3*(size_t)LHW]=a3; go[4*(size_t)LHW]=a4; go[5*(size_t)LHW]=a5;
  go[6*(size_t)LHW]=a6; go[7*(size_t)LHW]=a7; go[8*(size_t)LHW]=a8;
}

// ---------------- combine 9 shifted planes + bias + sigmoid ----------------
__global__ __launch_bounds__(256) void k_scores(const float* __restrict__ g,
                                                const float* __restrict__ bS,
                                                float* __restrict__ scores) {
  int gp = blockIdx.x * 256 + threadIdx.x;
  int l  = gp >> 15;
  int pi = gp & (HW - 1);
  int y = pi >> 8, x = pi & 255;
  float acc = bS[0];
  #pragma unroll
  for (int ky = 0; ky < 3; ++ky) {
    int yy = y + ky - 1;
    if (yy < 0 || yy >= HH) continue;
    #pragma unroll
    for (int kx = 0; kx < 3; ++kx) {
      int xx = x + kx - 1;
      if (xx < 0 || xx >= WW) continue;
      int tap = ky * 3 + kx;
      size_t q = (size_t)l * HW + yy * WW + xx;
      acc += g[(size_t)tap * LHW + q] + g[(size_t)(9 + tap) * LHW + q];
    }
  }
  scores[gp] = 1.0f / (1.0f + expf(-acc));
}

// ---------------- separable 9x9 maxpools ----------------
__global__ __launch_bounds__(256) void k_rowmax(const float* __restrict__ in, float* __restrict__ out) {
  int p = blockIdx.x * 256 + threadIdx.x;
  int x = p & 255;
  float m = -3.402823466e38f;
  #pragma unroll
  for (int dx = -4; dx <= 4; ++dx) {
    int xx = x + dx;
    if (xx >= 0 && xx < WW) m = fmaxf(m, in[p + dx]);
  }
  out[p] = m;
}

__device__ __forceinline__ float colmax9(const float* __restrict__ t1, int p) {
  int y = (p & (HW - 1)) >> 8;
  float m = -3.402823466e38f;
  #pragma unroll
  for (int dy = -4; dy <= 4; ++dy) {
    int yy = y + dy;
    if (yy >= 0 && yy < HH) m = fmaxf(m, t1[p + dy * WW]);
  }
  return m;
}

__global__ __launch_bounds__(256) void k_colmax_eqmask(const float* __restrict__ t1,
                                                       const float* __restrict__ scores,
                                                       float* __restrict__ mask) {
  int p = blockIdx.x * 256 + threadIdx.x;
  mask[p] = (colmax9(t1, p) == scores[p]) ? 1.0f : 0.0f;
}

__global__ __launch_bounds__(256) void k_colmax_supp(const float* __restrict__ t1,
                                                     const float* __restrict__ scores,
                                                     float* __restrict__ suppm,
                                                     float* __restrict__ supps) {
  int p = blockIdx.x * 256 + threadIdx.x;
  bool s = colmax9(t1, p) > 0.0f;
  suppm[p] = s ? 1.0f : 0.0f;
  supps[p] = s ? 0.0f : scores[p];
}

__global__ __launch_bounds__(256) void k_colmax_newmask(const float* __restrict__ t1,
                                                        const float* __restrict__ supps,
                                                        const float* __restrict__ suppm,
                                                        float* __restrict__ mask) {
  int p = blockIdx.x * 256 + threadIdx.x;
  float cm = colmax9(t1, p);
  bool nm = (supps[p] == cm) && (suppm[p] == 0.0f);
  mask[p] = (mask[p] != 0.0f || nm) ? 1.0f : 0.0f;
}

// ---------------- candidate collection ----------------
__global__ __launch_bounds__(256) void k_collect(const float* __restrict__ mask,
                                                 const float* __restrict__ scores,
                                                 int* __restrict__ cnt,
                                                 int* __restrict__ cidx,
                                                 float* __restrict__ csc) {
  int p = blockIdx.x * 256 + threadIdx.x;
  if (mask[p] != 0.0f) {
    int l = p >> 15;
    int pos = atomicAdd(&cnt[l], 1);
    if (pos < CAP) {
      cidx[l * CAP + pos] = p & (HW - 1);
      csc[l * CAP + pos]  = scores[p];
    }
  }
}

// ---------------- rank-based stable top-k (score desc, index asc) ----------------
__global__ __launch_bounds__(256) void k_rank(const int* __restrict__ cnt,
                                              const int* __restrict__ cidx,
                                              const float* __restrict__ csc,
                                              int* __restrict__ sel) {
  int b = blockIdx.x;            // 32 blocks: 8 per image
  int l = b >> 3;
  int M = cnt[l]; if (M > CAP) M = CAP;
  const int* ci = cidx + l * CAP;
  const float* cs = csc + l * CAP;
  for (int i = (b & 7) * 256 + threadIdx.x; i < M; i += 2048) {
    float si = cs[i]; int ii = ci[i];
    int rank = 0;
    for (int j = 0; j < M; ++j) {
      float sj = cs[j]; int ij = ci[j];
      rank += (sj > si || (sj == si && ij < ii)) ? 1 : 0;
    }
    if (rank < KP) sel[l * KP + rank] = ii;
  }
}

// ---------------- zero-score fill when #candidates < KP ----------------
__global__ __launch_bounds__(256) void k_fill(const int* __restrict__ cnt,
                                              const float* __restrict__ mask,
                                              int* __restrict__ sel) {
  int l = blockIdx.x, tid = threadIdx.x;
  int M = cnt[l]; if (M > CAP) M = CAP;
  int Mc = (M < KP) ? M : KP;
  int need = KP - Mc;
  if (need <= 0) return;                  // uniform across block
  __shared__ int csum[256];
  const float* mk = mask + (size_t)l * HW;
  const int per = HW / 256;               // 128
  int base = tid * per;
  int c = 0;
  for (int q = 0; q < per; ++q) c += (mk[base + q] == 0.0f) ? 1 : 0;
  int inc = c;
  csum[tid] = c;
  __syncthreads();
  for (int s = 1; s < 256; s <<= 1) {
    int v = (tid >= s) ? csum[tid - s] : 0;
    __syncthreads();
    csum[tid] += v;
    __syncthreads();
  }
  int excl = csum[tid] - inc;
  if (excl < need) {
    int r = excl;
    for (int q = 0; q < per && r < need; ++q) {
      if (mk[base + q] == 0.0f) { sel[l * KP + Mc + r] = base + q; ++r; }
    }
  }
}

// ---------------- desc conv (3x3, 256->128) at keypoints + relu + L2 norm ----------------
__global__ __launch_bounds__(128) void k_desc(const float* __restrict__ feats,
                                              const float* __restrict__ wT,
                                              const float* __restrict__ bD,
                                              const int* __restrict__ sel,
                                              float* __restrict__ dkp) {
  __shared__ float patch[4][CIN * 9];   // 36 KiB
  __shared__ int kpix[4];
  __shared__ float wsums[2][4];
  int b = blockIdx.x;
  int l = b >> 6;
  int k0 = (b & 63) * 4;
  int d = threadIdx.x;
  if (d < 4) kpix[d] = sel[l * KP + k0 + d];
  __syncthreads();
  for (int e = d; e < 4 * CIN * 9; e += 128) {
    int kp = e / (CIN * 9);
    int j  = e - kp * (CIN * 9);
    int c  = j / 9;
    int tap = j - c * 9;
    int ky = tap / 3, kx = tap - ky * 3;
    int pix = kpix[kp];
    int y = pix >> 8, x = pix & 255;
    int yy = y + ky - 1, xx = x + kx - 1;
    float v = 0.0f;
    if (yy >= 0 && yy < HH && xx >= 0 && xx < WW)
      v = feats[((size_t)(l * CIN + c) * HH + yy) * WW + xx];
    patch[kp][j] = v;
  }
  __syncthreads();
  float bv = bD[d];
  float a0 = bv, a1 = bv, a2 = bv, a3 = bv;
  for (int j = 0; j < CIN * 9; j += 4) {
    float4 p0 = *(const float4*)&patch[0][j];
    float4 p1 = *(const float4*)&patch[1][j];
    float4 p2 = *(const float4*)&patch[2][j];
    float4 p3 = *(const float4*)&patch[3][j];
    const float* q0 = (const float*)&p0;
    const float* q1 = (const float*)&p1;
    const float* q2 = (const float*)&p2;
    const float* q3 = (const float*)&p3;
    #pragma unroll
    for (int t = 0; t < 4; ++t) {
      float wv = wT[(size_t)(j + t) * CD + d];
      a0 = fmaf(wv, q0[t], a0);
      a1 = fmaf(wv, q1[t], a1);
      a2 = fmaf(wv, q2[t], a2);
      a3 = fmaf(wv, q3[t], a3);
    }
  }
  float r[4] = { fmaxf(a0, 0.f), fmaxf(a1, 0.f), fmaxf(a2, 0.f), fmaxf(a3, 0.f) };
  int lane = d & 63, wid = d >> 6;
  #pragma unroll
  for (int i = 0; i < 4; ++i) {
    float v = r[i] * r[i];
    #pragma unroll
    for (int s = 32; s > 0; s >>= 1) v += __shfl_down(v, s);
    if (lane == 0) wsums[wid][i] = v;
  }
  __syncthreads();
  #pragma unroll
  for (int i = 0; i < 4; ++i) {
    float nrm = fmaxf(sqrtf(wsums[0][i] + wsums[1][i]), 1e-12f);
    dkp[(size_t)(l * CD + d) * KP + k0 + i] = r[i] / nrm;
  }
}

// ---------------- cross-image attention per keypoint slot ----------------
__global__ __launch_bounds__(128) void k_attn(const float* __restrict__ dk, float* __restrict__ d2) {
  int k = blockIdx.x;
  int c = threadIdx.x;
  float q[LIMG];
  #pragma unroll
  for (int l = 0; l < LIMG; ++l) q[l] = dk[(size_t)(l * CD + c) * KP + k];
  __shared__ float qs[LIMG][CD];
  #pragma unroll
  for (int l = 0; l < LIMG; ++l) qs[l][c] = q[l];
  __syncthreads();
  __shared__ float dm[16];
  if (c < 16) {
    int n = c >> 2, m = c & 3;
    float s = 0.f;
    for (int t = 0; t < CD; ++t) s = fmaf(qs[n][t], qs[m][t], s);
    dm[c] = s * 0.08838834764831843f;     // 1/sqrt(128)
  }
  __syncthreads();
  #pragma unroll
  for (int n = 0; n < LIMG; ++n) {
    float a0 = dm[n*4+0], a1 = dm[n*4+1], a2 = dm[n*4+2], a3 = dm[n*4+3];
    float mx = fmaxf(fmaxf(a0, a1), fmaxf(a2, a3));
    float e0 = expf(a0 - mx), e1 = expf(a1 - mx), e2 = expf(a2 - mx), e3 = expf(a3 - mx);
    float inv = 1.0f / (e0 + e1 + e2 + e3);
    float msg = (e0 * q[0] + e1 * q[1] + e2 * q[2] + e3 * q[3]) * inv;
    d2[(size_t)(n * CD + c) * KP + k] = 2.0f * q[n] + msg;
  }
}

// ---------------- conv1d k=3 pad=1 + relu ----------------
__global__ __launch_bounds__(256) void k_proj(const float* __restrict__ d2, const float* __restrict__ pw,
                                              const float* __restrict__ pb, float* __restrict__ d3) {
  int b = blockIdx.x;
  int l = b >> 7, o = b & 127;
  int k = threadIdx.x;
  float acc = pb[o];
  for (int c = 0; c < CD; ++c) {
    const float* row = d2 + (size_t)(l * CD + c) * KP;
    float xm = (k > 0)      ? row[k - 1] : 0.f;
    float x0 = row[k];
    float xp = (k < KP - 1) ? row[k + 1] : 0.f;
    const float* w = pw + (size_t)(o * CD + c) * 3;
    acc = fmaf(w[0], xm, acc);
    acc = fmaf(w[1], x0, acc);
    acc = fmaf(w[2], xp, acc);
  }
  d3[(size_t)(l * CD + o) * KP + k] = fmaxf(acc, 0.f);
}

// ---------------- conv1d k=1 ----------------
__global__ __launch_bounds__(256) void k_projS(const float* __restrict__ d3, const float* __restrict__ psw,
                                               const float* __restrict__ psb, float* __restrict__ sb) {
  int b = blockIdx.x;
  int l = b >> 7, o = b & 127;
  int k = threadIdx.x;
  float acc = psb[o];
  for (int c = 0; c < CD; ++c)
    acc = fmaf(psw[o * CD + c], d3[(size_t)(l * CD + c) * KP + k], acc);
  sb[(size_t)(l * CD + o) * KP + k] = acc;
}

// ---------------- stable descending argsort per row + gather ----------------
__global__ __launch_bounds__(256) void k_sort(const float* __restrict__ sb, const float* __restrict__ d3,
                                              float* __restrict__ d4) {
  int base = blockIdx.x * KP;     // blockIdx = l*CD+o
  int j = threadIdx.x;
  __shared__ float srow[KP];
  float sj = sb[base + j];
  srow[j] = sj;
  __syncthreads();
  int rank = 0;
  for (int m = 0; m < KP; ++m) {
    float sm = srow[m];
    rank += (sm > sj || (sm == sj && m < j)) ? 1 : 0;
  }
  d4[base + rank] = d3[base + j];
}

// ---------------- final conv1d (128->3) ----------------
__global__ __launch_bounds__(256) void k_finalval(const float* __restrict__ d4, const float* __restrict__ fw,
                                                  const float* __restrict__ fb, float* __restrict__ fval) {
  int b = blockIdx.x;         // l*3+o
  int o = b % 3, l = b / 3;
  int k = threadIdx.x;
  float acc = fb[o];
  for (int c = 0; c < CD; ++c)
    acc = fmaf(fw[o * CD + c], d4[(size_t)(l * CD + c) * KP + k], acc);
  fval[b * KP + k] = acc;
}

// ---------------- min|diff| -> theta ----------------
__global__ __launch_bounds__(256) void k_theta(const float* __restrict__ fval, float* __restrict__ theta) {
  int k = threadIdx.x;
  __shared__ float sv[256];
  __shared__ float res[LIMG][3];
  for (int l = 0; l < LIMG; ++l) {
    for (int o = 0; o < 3; ++o) {
      float dv = fval[(l * 3 + o) * KP + k] - fval[o * KP + k];
      sv[k] = fabsf(dv);
      __syncthreads();
      for (int s = 128; s > 0; s >>= 1) {
        if (k < s) sv[k] = fminf(sv[k], sv[k + s]);
        __syncthreads();
      }
      if (k == 0) res[l][o] = sv[0];
      __syncthreads();
    }
  }
  if (k == 0) {
    for (int l = 0; l < LIMG; ++l) {
      float tx = res[l][0], ty = res[l][1], th = res[l][2];
      float cth = cosf(th), sth = sinf(th);
      theta[l*6+0] = cth;  theta[l*6+1] = -sth; theta[l*6+2] = tx;
      theta[l*6+3] = sth;  theta[l*6+4] = cth;  theta[l*6+5] = ty;
    }
  }
}

// ---------------- bilinear grid sample ----------------
__global__ __launch_bounds__(256) void k_sample(const float* __restrict__ feats,
                                                const float* __restrict__ theta,
                                                float* __restrict__ out) {
  int gid = blockIdx.x * 256 + threadIdx.x;
  int x = gid & 255;
  int y = (gid >> 8) & 127;
  int l = gid >> 23;
  const float* t = theta + l * 6;
  float X = (x + 0.5f) * (2.0f / WW) - 1.0f;
  float Y = (y + 0.5f) * (2.0f / HH) - 1.0f;
  float gx = t[0] * X + t[1] * Y + t[2];
  float gy = t[3] * X + t[4] * Y + t[5];
  float ix = ((gx + 1.0f) * WW - 1.0f) * 0.5f;
  float iy = ((gy + 1.0f) * HH - 1.0f) * 0.5f;
  float x0 = floorf(ix), y0 = floorf(iy);
  float x1 = x0 + 1.0f,  y1 = y0 + 1.0f;
  const float* img = feats + ((size_t)(gid >> 15) << 15);   // (l*CIN+c)*HW
  float wa = (x1 - ix) * (y1 - iy);
  float wb = (ix - x0) * (y1 - iy);
  float wc = (x1 - ix) * (iy - y0);
  float wd = (ix - x0) * (iy - y0);
  float acc;
  {
    bool v = (x0 >= 0.f) && (x0 <= (float)(WW-1)) && (y0 >= 0.f) && (y0 <= (float)(HH-1));
    int xc = (int)fminf(fmaxf(x0, 0.f), (float)(WW-1));
    int yc = (int)fminf(fmaxf(y0, 0.f), (float)(HH-1));
    acc = (v ? img[yc * WW + xc] : 0.f) * wa;
  }
  {
    bool v = (x1 >= 0.f) && (x1 <= (float)(WW-1)) && (y0 >= 0.f) && (y0 <= (float)(HH-1));
    int xc = (int)fminf(fmaxf(x1, 0.f), (float)(WW-1));
    int yc = (int)fminf(fmaxf(y0, 0.f), (float)(HH-1));
    acc += (v ? img[yc * WW + xc] : 0.f) * wb;
  }
  {
    bool v = (x0 >= 0.f) && (x0 <= (float)(WW-1)) && (y1 >= 0.f) && (y1 <= (float)(HH-1));
    int xc = (int)fminf(fmaxf(x0, 0.f), (float)(WW-1));
    int yc = (int)fminf(fmaxf(y1, 0.f), (float)(HH-1));
    acc += (v ? img[yc * WW + xc] : 0.f) * wc;
  }
  {
    bool v = (x1 >= 0.f) && (x1 <= (float)(WW-1)) && (y1 >= 0.f) && (y1 <= (float)(HH-1));
    int xc = (int)fminf(fmaxf(x1, 0.f), (float)(WW-1));
    int yc = (int)fminf(fmaxf(y1, 0.f), (float)(HH-1));
    acc += (v ? img[yc * WW + xc] : 0.f) * wd;
  }
  out[gid] = acc;
}

extern "C" void kernel_launch(void* const* d_in, const int* in_sizes, int n_in,
                              void* d_out, int out_size, void* d_ws, size_t ws_size,
                              hipStream_t stream) {
  const float* feats = (const float*)d_in[0];
  const float* wS    = (const float*)d_in[1];
  const float* bS    = (const float*)d_in[2];
  const float* wD    = (const float*)d_in[3];
  const float* bD    = (const float*)d_in[4];
  const float* pw    = (const float*)d_in[5];
  const float* pb    = (const float*)d_in[6];
  const float* psw   = (const float*)d_in[7];
  const float* psb   = (const float*)d_in[8];
  const float* fw    = (const float*)d_in[9];
  const float* fb    = (const float*)d_in[10];
  float* out = (float*)d_out;

  char* base = (char*)d_ws;
  size_t off = 0;
  auto alloc = [&](size_t bytes) -> void* {
    void* p = base + off;
    off = (off + bytes + 255) & ~(size_t)255;
    return p;
  };
  float* g      = (float*)alloc((size_t)NSP * 9 * LHW * sizeof(float));
  float* scores = (float*)alloc((size_t)LHW * 4);
  float* t1     = (float*)alloc((size_t)LHW * 4);
  float* mask   = (float*)alloc((size_t)LHW * 4);
  float* suppm  = (float*)alloc((size_t)LHW * 4);
  float* supps  = (float*)alloc((size_t)LHW * 4);
  float* dkp    = (float*)alloc((size_t)LHW * 4);
  float* d2     = (float*)alloc((size_t)LHW * 4);
  float* d3     = (float*)alloc((size_t)LHW * 4);
  float* sb     = (float*)alloc((size_t)LHW * 4);
  float* d4     = (float*)alloc((size_t)LHW * 4);
  float* wT     = (float*)alloc((size_t)CIN * 9 * CD * 4);
  float* fval   = (float*)alloc((size_t)12 * KP * 4);
  float* theta  = (float*)alloc(24 * 4);
  float* csc    = (float*)alloc((size_t)LIMG * CAP * 4);
  int*   cidx   = (int*)  alloc((size_t)LIMG * CAP * 4);
  int*   cnt    = (int*)  alloc(64);
  int*   sel    = (int*)  alloc((size_t)LIMG * KP * 4);

  k_init<<<1, 64, 0, stream>>>(cnt);
  k_wtrans<<<(CD * CIN * 9 + 255) / 256, 256, 0, stream>>>(wD, wT);
  k_chanred<<<NSP * 512, 256, 0, stream>>>(feats, wS, g);
  k_scores<<<512, 256, 0, stream>>>(g, bS, scores);
  k_rowmax<<<512, 256, 0, stream>>>(scores, t1);
  k_colmax_eqmask<<<512, 256, 0, stream>>>(t1, scores, mask);
  for (int it = 0; it < 2; ++it) {
    k_rowmax<<<512, 256, 0, stream>>>(mask, t1);
    k_colmax_supp<<<512, 256, 0, stream>>>(t1, scores, suppm, supps);
    k_rowmax<<<512, 256, 0, stream>>>(supps, t1);
    k_colmax_newmask<<<512, 256, 0, stream>>>(t1, supps, suppm, mask);
  }
  k_collect<<<512, 256, 0, stream>>>(mask, scores, cnt, cidx, csc);
  k_rank<<<32, 256, 0, stream>>>(cnt, cidx, csc, sel);
  k_fill<<<LIMG, 256, 0, stream>>>(cnt, mask, sel);
  k_desc<<<256, 128, 0, stream>>>(feats, wT, bD, sel, dkp);
  k_attn<<<256, 128, 0, stream>>>(dkp, d2);
  k_proj<<<512, 256, 0, stream>>>(d2, pw, pb, d3);
  k_projS<<<512, 256, 0, stream>>>(d3, psw, psb, sb);
  k_sort<<<512, 256, 0, stream>>>(sb, d3, d4);
  k_finalval<<<12, 256, 0, stream>>>(d4, fw, fb, fval);
  k_theta<<<1, 256, 0, stream>>>(fval, theta);
  k_sample<<<LHW * CIN / 256, 256, 0, stream>>>(feats, theta, out);
}

// Round 2
// 382.213 us; speedup vs baseline: 1.1365x; 1.1365x over previous
//
#include <hip/hip_runtime.h>

#define LIMG 4
#define CIN 256
#define HH 128
#define WW 256
#define HW 32768          // HH*WW
#define LHW 131072        // LIMG*HW
#define CD 128
#define KP 256
#define CAP 8192
#define NSP 2
#define CPER (CIN/NSP)    // 128
#define NINF -3.402823466e38f

// ---------------- init ----------------
__global__ void k_init(int* __restrict__ cnt) {
  int t = threadIdx.x;
  if (t < LIMG) cnt[t] = 0;
}

// ---------------- transpose convD weights: wT[(c*9+tap)*CD + d] ----------------
__global__ void k_wtrans(const float* __restrict__ wD, float* __restrict__ wT) {
  int i = blockIdx.x * 256 + threadIdx.x;
  if (i >= CD * CIN * 9) return;
  int d = i & (CD - 1);
  int j = i >> 7;                    // c*9+tap
  wT[i] = wD[d * (CIN * 9) + j];
}

// ---------------- channel-reduced score planes ----------------
__global__ __launch_bounds__(256) void k_chanred(const float* __restrict__ feats,
                                                 const float* __restrict__ wS,
                                                 float* __restrict__ g) {
  int gp   = (blockIdx.x & 511) * 256 + threadIdx.x;  // 0..131071
  int half = blockIdx.x >> 9;                         // 0..NSP-1
  int l  = gp >> 15;
  int pi = gp & (HW - 1);
  const float* f = feats + (size_t)(l * CIN + half * CPER) * HW + pi;
  const float* w = wS + half * CPER * 9;
  float a0=0,a1=0,a2=0,a3=0,a4=0,a5=0,a6=0,a7=0,a8=0;
  #pragma unroll 4
  for (int c = 0; c < CPER; ++c) {
    float v = f[(size_t)c * HW];
    const float* wc = w + c * 9;
    a0 = fmaf(wc[0], v, a0); a1 = fmaf(wc[1], v, a1); a2 = fmaf(wc[2], v, a2);
    a3 = fmaf(wc[3], v, a3); a4 = fmaf(wc[4], v, a4); a5 = fmaf(wc[5], v, a5);
    a6 = fmaf(wc[6], v, a6); a7 = fmaf(wc[7], v, a7); a8 = fmaf(wc[8], v, a8);
  }
  float* go = g + (size_t)(half * 9) * LHW + gp;
  go[0*(size_t)LHW]=a0; go[1*(size_t)LHW]=a1; go[2*(size_t)LHW]=a2;
  go[3*(size_t)LHW]=a3; go[4*(size_t)LHW]=a4; go[5*(size_t)LHW]=a5;
  go[6*(size_t)LHW]=a6; go[7*(size_t)LHW]=a7; go[8*(size_t)LHW]=a8;
}

// ---------------- combine 9 shifted planes + bias + sigmoid ----------------
__global__ __launch_bounds__(256) void k_scores(const float* __restrict__ g,
                                                const float* __restrict__ bS,
                                                float* __restrict__ scores) {
  int gp = blockIdx.x * 256 + threadIdx.x;
  int l  = gp >> 15;
  int pi = gp & (HW - 1);
  int y = pi >> 8, x = pi & 255;
  float acc = bS[0];
  #pragma unroll
  for (int ky = 0; ky < 3; ++ky) {
    int yy = y + ky - 1;
    if (yy < 0 || yy >= HH) continue;
    #pragma unroll
    for (int kx = 0; kx < 3; ++kx) {
      int xx = x + kx - 1;
      if (xx < 0 || xx >= WW) continue;
      int tap = ky * 3 + kx;
      size_t q = (size_t)l * HW + yy * WW + xx;
      acc += g[(size_t)tap * LHW + q] + g[(size_t)(9 + tap) * LHW + q];
    }
  }
  scores[gp] = 1.0f / (1.0f + expf(-acc));
}

// ---------------- fused 9x9 maxpool + elementwise (NMS ladder) ----------------
// mode 0: mask = (pool(scores) == scores)          [in = scores]
// mode 1: suppm = pool(mask) > 0; supps = suppm?0:scores   [in = mask]
// mode 2: mask |= (supps == pool(supps)) & !suppm  [in = supps]
#define PROWS 8
__global__ __launch_bounds__(256) void k_nms(int mode,
                                             const float* __restrict__ in,
                                             const float* __restrict__ scores,
                                             float* __restrict__ suppm,
                                             float* __restrict__ supps,
                                             float* __restrict__ mask) {
  __shared__ float raw[PROWS + 8][WW];
  __shared__ float rm[PROWS + 8][WW];
  int b = blockIdx.x;
  int l = b >> 4;                 // HH/PROWS = 16
  int y0 = (b & 15) * PROWS;
  int x = threadIdx.x;
  const float* inl = in + (size_t)l * HW;
  #pragma unroll
  for (int r = 0; r < PROWS + 8; ++r) {
    int yy = y0 - 4 + r;
    raw[r][x] = (yy >= 0 && yy < HH) ? inl[yy * WW + x] : NINF;
  }
  __syncthreads();
  #pragma unroll
  for (int r = 0; r < PROWS + 8; ++r) {
    float m = NINF;
    #pragma unroll
    for (int dx = -4; dx <= 4; ++dx) {
      int xx = x + dx;
      if (xx >= 0 && xx < WW) m = fmaxf(m, raw[r][xx]);
    }
    rm[r][x] = m;
  }
  __syncthreads();
  #pragma unroll
  for (int r = 0; r < PROWS; ++r) {
    float m = NINF;
    #pragma unroll
    for (int t = 0; t < 9; ++t) m = fmaxf(m, rm[r + t][x]);
    int p = l * HW + (y0 + r) * WW + x;
    float ctr = raw[r + 4][x];
    if (mode == 0) {
      mask[p] = (m == ctr) ? 1.0f : 0.0f;
    } else if (mode == 1) {
      bool s = m > 0.0f;
      suppm[p] = s ? 1.0f : 0.0f;
      supps[p] = s ? 0.0f : scores[p];
    } else {
      bool nm = (ctr == m) && (suppm[p] == 0.0f);
      mask[p] = (mask[p] != 0.0f || nm) ? 1.0f : 0.0f;
    }
  }
}

// ---------------- candidate collection ----------------
__global__ __launch_bounds__(256) void k_collect(const float* __restrict__ mask,
                                                 const float* __restrict__ scores,
                                                 int* __restrict__ cnt,
                                                 int* __restrict__ cidx,
                                                 float* __restrict__ csc) {
  int p = blockIdx.x * 256 + threadIdx.x;
  if (mask[p] != 0.0f) {
    int l = p >> 15;
    int pos = atomicAdd(&cnt[l], 1);
    if (pos < CAP) {
      cidx[l * CAP + pos] = p & (HW - 1);
      csc[l * CAP + pos]  = scores[p];
    }
  }
}

// ---------------- rank-based stable top-k (score desc, index asc) ----------------
__global__ __launch_bounds__(256) void k_rank(const int* __restrict__ cnt,
                                              const int* __restrict__ cidx,
                                              const float* __restrict__ csc,
                                              int* __restrict__ sel) {
  int b = blockIdx.x;            // 32 blocks: 8 per image
  int l = b >> 3;
  int M = cnt[l]; if (M > CAP) M = CAP;
  const int* ci = cidx + l * CAP;
  const float* cs = csc + l * CAP;
  for (int i = (b & 7) * 256 + threadIdx.x; i < M; i += 2048) {
    float si = cs[i]; int ii = ci[i];
    int rank = 0;
    for (int j = 0; j < M; ++j) {
      float sj = cs[j]; int ij = ci[j];
      rank += (sj > si || (sj == si && ij < ii)) ? 1 : 0;
    }
    if (rank < KP) sel[l * KP + rank] = ii;
  }
}

// ---------------- zero-score fill when #candidates < KP ----------------
__global__ __launch_bounds__(256) void k_fill(const int* __restrict__ cnt,
                                              const float* __restrict__ mask,
                                              int* __restrict__ sel) {
  int l = blockIdx.x, tid = threadIdx.x;
  int M = cnt[l]; if (M > CAP) M = CAP;
  int Mc = (M < KP) ? M : KP;
  int need = KP - Mc;
  if (need <= 0) return;                  // uniform across block
  __shared__ int csum[256];
  const float* mk = mask + (size_t)l * HW;
  const int per = HW / 256;               // 128
  int base = tid * per;
  int c = 0;
  for (int q = 0; q < per; ++q) c += (mk[base + q] == 0.0f) ? 1 : 0;
  int inc = c;
  csum[tid] = c;
  __syncthreads();
  for (int s = 1; s < 256; s <<= 1) {
    int v = (tid >= s) ? csum[tid - s] : 0;
    __syncthreads();
    csum[tid] += v;
    __syncthreads();
  }
  int excl = csum[tid] - inc;
  if (excl < need) {
    int r = excl;
    for (int q = 0; q < per && r < need; ++q) {
      if (mk[base + q] == 0.0f) { sel[l * KP + Mc + r] = base + q; ++r; }
    }
  }
}

// ---------------- desc conv phase 1: split-K partial sums ----------------
// grid: L * 64 kp-groups * 4 channel-quarters = 1024 blocks, 256 threads
// pacc[q][l][k][d]
__global__ __launch_bounds__(256) void k_desc1(const float* __restrict__ feats,
                                               const float* __restrict__ wT,
                                               const int* __restrict__ sel,
                                               float* __restrict__ pacc) {
  __shared__ float patch[4][576];     // 4 kp x (64 ch * 9 taps)
  __shared__ int kpix[4];
  int b = blockIdx.x;
  int q  = b & 3;
  int kb = (b >> 2) & 63;
  int l  = b >> 8;
  int k0 = kb * 4;
  int tid = threadIdx.x;
  if (tid < 4) kpix[tid] = sel[l * KP + k0 + tid];
  __syncthreads();
  int c0 = q * 64;
  for (int e = tid; e < 4 * 576; e += 256) {
    int kp = e / 576;
    int j  = e - kp * 576;
    int c  = j / 9;
    int tap = j - c * 9;
    int ky = tap / 3, kx = tap - ky * 3;
    int pix = kpix[kp];
    int y = pix >> 8, x = pix & 255;
    int yy = y + ky - 1, xx = x + kx - 1;
    float v = 0.0f;
    if (yy >= 0 && yy < HH && xx >= 0 && xx < WW)
      v = feats[((size_t)(l * CIN + c0 + c) * HH + yy) * WW + xx];
    patch[kp][j] = v;
  }
  __syncthreads();
  int d = tid & 127;
  int g = tid >> 7;                    // 0,1 -> kp pair (2g, 2g+1)
  const float* pa = patch[2 * g];
  const float* pb = patch[2 * g + 1];
  const float* w = wT + (size_t)(q * 576) * CD + d;
  float a0 = 0.f, a1 = 0.f;
  #pragma unroll 4
  for (int j = 0; j < 576; j += 4) {
    float4 qa = *(const float4*)&pa[j];
    float4 qb = *(const float4*)&pb[j];
    float w0 = w[(size_t)(j + 0) * CD];
    float w1 = w[(size_t)(j + 1) * CD];
    float w2 = w[(size_t)(j + 2) * CD];
    float w3 = w[(size_t)(j + 3) * CD];
    a0 = fmaf(w0, qa.x, a0); a1 = fmaf(w0, qb.x, a1);
    a0 = fmaf(w1, qa.y, a0); a1 = fmaf(w1, qb.y, a1);
    a0 = fmaf(w2, qa.z, a0); a1 = fmaf(w2, qb.z, a1);
    a0 = fmaf(w3, qa.w, a0); a1 = fmaf(w3, qb.w, a1);
  }
  size_t base = (((size_t)q * LIMG + l) * KP + k0) * CD + d;
  pacc[base + (size_t)(2 * g) * CD]     = a0;
  pacc[base + (size_t)(2 * g + 1) * CD] = a1;
}

// ---------------- desc conv phase 2: combine + bias + relu + L2 norm ----------------
// grid: L*KP = 1024 blocks, 128 threads (one per output channel)
__global__ __launch_bounds__(128) void k_desc2(const float* __restrict__ pacc,
                                               const float* __restrict__ bD,
                                               float* __restrict__ dkp) {
  __shared__ float ps[2];
  int b = blockIdx.x;
  int l = b >> 8, k = b & 255;
  int d = threadIdx.x;
  float s = bD[d];
  #pragma unroll
  for (int q = 0; q < 4; ++q)
    s += pacc[(((size_t)q * LIMG + l) * KP + k) * CD + d];
  float r = fmaxf(s, 0.0f);
  float v = r * r;
  #pragma unroll
  for (int sh = 32; sh > 0; sh >>= 1) v += __shfl_down(v, sh);
  if ((d & 63) == 0) ps[d >> 6] = v;
  __syncthreads();
  float n = fmaxf(sqrtf(ps[0] + ps[1]), 1e-12f);
  dkp[(size_t)(l * CD + d) * KP + k] = r / n;
}

// ---------------- cross-image attention per keypoint slot ----------------
__global__ __launch_bounds__(128) void k_attn(const float* __restrict__ dk, float* __restrict__ d2) {
  int k = blockIdx.x;
  int c = threadIdx.x;
  float q[LIMG];
  #pragma unroll
  for (int l = 0; l < LIMG; ++l) q[l] = dk[(size_t)(l * CD + c) * KP + k];
  __shared__ float qs[LIMG][CD];
  #pragma unroll
  for (int l = 0; l < LIMG; ++l) qs[l][c] = q[l];
  __syncthreads();
  __shared__ float dm[16];
  if (c < 16) {
    int n = c >> 2, m = c & 3;
    float s = 0.f;
    for (int t = 0; t < CD; ++t) s = fmaf(qs[n][t], qs[m][t], s);
    dm[c] = s * 0.08838834764831843f;     // 1/sqrt(128)
  }
  __syncthreads();
  #pragma unroll
  for (int n = 0; n < LIMG; ++n) {
    float a0 = dm[n*4+0], a1 = dm[n*4+1], a2 = dm[n*4+2], a3 = dm[n*4+3];
    float mx = fmaxf(fmaxf(a0, a1), fmaxf(a2, a3));
    float e0 = expf(a0 - mx), e1 = expf(a1 - mx), e2 = expf(a2 - mx), e3 = expf(a3 - mx);
    float inv = 1.0f / (e0 + e1 + e2 + e3);
    float msg = (e0 * q[0] + e1 * q[1] + e2 * q[2] + e3 * q[3]) * inv;
    d2[(size_t)(n * CD + c) * KP + k] = 2.0f * q[n] + msg;
  }
}

// ---------------- conv1d k=3 pad=1 + relu ----------------
__global__ __launch_bounds__(256) void k_proj(const float* __restrict__ d2, const float* __restrict__ pw,
                                              const float* __restrict__ pb, float* __restrict__ d3) {
  int b = blockIdx.x;
  int l = b >> 7, o = b & 127;
  int k = threadIdx.x;
  float acc = pb[o];
  for (int c = 0; c < CD; ++c) {
    const float* row = d2 + (size_t)(l * CD + c) * KP;
    float xm = (k > 0)      ? row[k - 1] : 0.f;
    float x0 = row[k];
    float xp = (k < KP - 1) ? row[k + 1] : 0.f;
    const float* w = pw + (size_t)(o * CD + c) * 3;
    acc = fmaf(w[0], xm, acc);
    acc = fmaf(w[1], x0, acc);
    acc = fmaf(w[2], xp, acc);
  }
  d3[(size_t)(l * CD + o) * KP + k] = fmaxf(acc, 0.f);
}

// ---------------- conv1d k=1 ----------------
__global__ __launch_bounds__(256) void k_projS(const float* __restrict__ d3, const float* __restrict__ psw,
                                               const float* __restrict__ psb, float* __restrict__ sb) {
  int b = blockIdx.x;
  int l = b >> 7, o = b & 127;
  int k = threadIdx.x;
  float acc = psb[o];
  for (int c = 0; c < CD; ++c)
    acc = fmaf(psw[o * CD + c], d3[(size_t)(l * CD + c) * KP + k], acc);
  sb[(size_t)(l * CD + o) * KP + k] = acc;
}

// ---------------- stable descending argsort per row + gather ----------------
__global__ __launch_bounds__(256) void k_sort(const float* __restrict__ sb, const float* __restrict__ d3,
                                              float* __restrict__ d4) {
  int base = blockIdx.x * KP;     // blockIdx = l*CD+o
  int j = threadIdx.x;
  __shared__ float srow[KP];
  float sj = sb[base + j];
  srow[j] = sj;
  __syncthreads();
  int rank = 0;
  for (int m = 0; m < KP; ++m) {
    float sm = srow[m];
    rank += (sm > sj || (sm == sj && m < j)) ? 1 : 0;
  }
  d4[base + rank] = d3[base + j];
}

// ---------------- final conv1d (128->3) ----------------
__global__ __launch_bounds__(256) void k_finalval(const float* __restrict__ d4, const float* __restrict__ fw,
                                                  const float* __restrict__ fb, float* __restrict__ fval) {
  int b = blockIdx.x;         // l*3+o
  int o = b % 3, l = b / 3;
  int k = threadIdx.x;
  float acc = fb[o];
  for (int c = 0; c < CD; ++c)
    acc = fmaf(fw[o * CD + c], d4[(size_t)(l * CD + c) * KP + k], acc);
  fval[b * KP + k] = acc;
}

// ---------------- min|diff| -> theta ----------------
__global__ __launch_bounds__(256) void k_theta(const float* __restrict__ fval, float* __restrict__ theta) {
  int k = threadIdx.x;
  __shared__ float sv[256];
  __shared__ float res[LIMG][3];
  for (int l = 0; l < LIMG; ++l) {
    for (int o = 0; o < 3; ++o) {
      float dv = fval[(l * 3 + o) * KP + k] - fval[o * KP + k];
      sv[k] = fabsf(dv);
      __syncthreads();
      for (int s = 128; s > 0; s >>= 1) {
        if (k < s) sv[k] = fminf(sv[k], sv[k + s]);
        __syncthreads();
      }
      if (k == 0) res[l][o] = sv[0];
      __syncthreads();
    }
  }
  if (k == 0) {
    for (int l = 0; l < LIMG; ++l) {
      float tx = res[l][0], ty = res[l][1], th = res[l][2];
      float cth = cosf(th), sth = sinf(th);
      theta[l*6+0] = cth;  theta[l*6+1] = -sth; theta[l*6+2] = tx;
      theta[l*6+3] = sth;  theta[l*6+4] = cth;  theta[l*6+5] = ty;
    }
  }
}

// ---------------- bilinear grid sample: 4 channels per thread ----------------
// grid: L * CIN/4 * HW/256 = 4*64*128 = 32768 blocks
__global__ __launch_bounds__(256) void k_sample(const float* __restrict__ feats,
                                                const float* __restrict__ theta,
                                                float* __restrict__ out) {
  int b = blockIdx.x;
  int pb = b & 127;
  int cg = (b >> 7) & 63;
  int l  = b >> 13;
  int pi = pb * 256 + threadIdx.x;
  int x = pi & 255, y = pi >> 8;
  const float* t = theta + l * 6;
  float X = (x + 0.5f) * (2.0f / WW) - 1.0f;
  float Y = (y + 0.5f) * (2.0f / HH) - 1.0f;
  float gx = t[0] * X + t[1] * Y + t[2];
  float gy = t[3] * X + t[4] * Y + t[5];
  float ix = ((gx + 1.0f) * WW - 1.0f) * 0.5f;
  float iy = ((gy + 1.0f) * HH - 1.0f) * 0.5f;
  float x0 = floorf(ix), y0 = floorf(iy);
  float x1 = x0 + 1.0f,  y1 = y0 + 1.0f;
  float wa = (x1 - ix) * (y1 - iy);
  float wb = (ix - x0) * (y1 - iy);
  float wc = (x1 - ix) * (iy - y0);
  float wd = (ix - x0) * (iy - y0);
  bool vx0 = (x0 >= 0.f) && (x0 <= (float)(WW-1));
  bool vx1 = (x1 >= 0.f) && (x1 <= (float)(WW-1));
  bool vy0 = (y0 >= 0.f) && (y0 <= (float)(HH-1));
  bool vy1 = (y1 >= 0.f) && (y1 <= (float)(HH-1));
  wa = (vx0 && vy0) ? wa : 0.f;
  wb = (vx1 && vy0) ? wb : 0.f;
  wc = (vx0 && vy1) ? wc : 0.f;
  wd = (vx1 && vy1) ? wd : 0.f;
  int xc0 = (int)fminf(fmaxf(x0, 0.f), (float)(WW-1));
  int xc1 = (int)fminf(fmaxf(x1, 0.f), (float)(WW-1));
  int yc0 = (int)fminf(fmaxf(y0, 0.f), (float)(HH-1));
  int yc1 = (int)fminf(fmaxf(y1, 0.f), (float)(HH-1));
  int o00 = yc0 * WW + xc0;
  int o10 = yc0 * WW + xc1;
  int o01 = yc1 * WW + xc0;
  int o11 = yc1 * WW + xc1;
  const float* img = feats + (size_t)(l * CIN + cg * 4) * HW;
  float* op = out + (size_t)(l * CIN + cg * 4) * HW + pi;
  #pragma unroll
  for (int i = 0; i < 4; ++i) {
    const float* im = img + (size_t)i * HW;
    float acc = im[o00] * wa + im[o10] * wb + im[o01] * wc + im[o11] * wd;
    op[(size_t)i * HW] = acc;
  }
}

extern "C" void kernel_launch(void* const* d_in, const int* in_sizes, int n_in,
                              void* d_out, int out_size, void* d_ws, size_t ws_size,
                              hipStream_t stream) {
  const float* feats = (const float*)d_in[0];
  const float* wS    = (const float*)d_in[1];
  const float* bS    = (const float*)d_in[2];
  const float* wD    = (const float*)d_in[3];
  const float* bD    = (const float*)d_in[4];
  const float* pw    = (const float*)d_in[5];
  const float* pb    = (const float*)d_in[6];
  const float* psw   = (const float*)d_in[7];
  const float* psb   = (const float*)d_in[8];
  const float* fw    = (const float*)d_in[9];
  const float* fb    = (const float*)d_in[10];
  float* out = (float*)d_out;

  char* base = (char*)d_ws;
  size_t off = 0;
  auto alloc = [&](size_t bytes) -> void* {
    void* p = base + off;
    off = (off + bytes + 255) & ~(size_t)255;
    return p;
  };
  float* g      = (float*)alloc((size_t)NSP * 9 * LHW * sizeof(float));
  float* scores = (float*)alloc((size_t)LHW * 4);
  float* mask   = (float*)alloc((size_t)LHW * 4);
  float* suppm  = (float*)alloc((size_t)LHW * 4);
  float* supps  = (float*)alloc((size_t)LHW * 4);
  float* dkp    = (float*)alloc((size_t)LHW * 4);
  float* d2     = (float*)alloc((size_t)LHW * 4);
  float* d3     = (float*)alloc((size_t)LHW * 4);
  float* sb     = (float*)alloc((size_t)LHW * 4);
  float* d4     = (float*)alloc((size_t)LHW * 4);
  float* wT     = (float*)alloc((size_t)CIN * 9 * CD * 4);
  float* pacc   = (float*)alloc((size_t)4 * LIMG * KP * CD * 4);
  float* fval   = (float*)alloc((size_t)12 * KP * 4);
  float* theta  = (float*)alloc(24 * 4);
  float* csc    = (float*)alloc((size_t)LIMG * CAP * 4);
  int*   cidx   = (int*)  alloc((size_t)LIMG * CAP * 4);
  int*   cnt    = (int*)  alloc(64);
  int*   sel    = (int*)  alloc((size_t)LIMG * KP * 4);

  k_init<<<1, 64, 0, stream>>>(cnt);
  k_wtrans<<<(CD * CIN * 9 + 255) / 256, 256, 0, stream>>>(wD, wT);
  k_chanred<<<NSP * 512, 256, 0, stream>>>(feats, wS, g);
  k_scores<<<512, 256, 0, stream>>>(g, bS, scores);
  k_nms<<<64, 256, 0, stream>>>(0, scores, scores, suppm, supps, mask);
  for (int it = 0; it < 2; ++it) {
    k_nms<<<64, 256, 0, stream>>>(1, mask,  scores, suppm, supps, mask);
    k_nms<<<64, 256, 0, stream>>>(2, supps, scores, suppm, supps, mask);
  }
  k_collect<<<512, 256, 0, stream>>>(mask, scores, cnt, cidx, csc);
  k_rank<<<32, 256, 0, stream>>>(cnt, cidx, csc, sel);
  k_fill<<<LIMG, 256, 0, stream>>>(cnt, mask, sel);
  k_desc1<<<1024, 256, 0, stream>>>(feats, wT, sel, pacc);
  k_desc2<<<1024, 128, 0, stream>>>(pacc, bD, dkp);
  k_attn<<<256, 128, 0, stream>>>(dkp, d2);
  k_proj<<<512, 256, 0, stream>>>(d2, pw, pb, d3);
  k_projS<<<512, 256, 0, stream>>>(d3, psw, psb, sb);
  k_sort<<<512, 256, 0, stream>>>(sb, d3, d4);
  k_finalval<<<12, 256, 0, stream>>>(d4, fw, fb, fval);
  k_theta<<<1, 256, 0, stream>>>(fval, theta);
  k_sample<<<32768, 256, 0, stream>>>(feats, theta, out);
}

// Round 3
// 302.004 us; speedup vs baseline: 1.4383x; 1.2656x over previous
//
#include <hip/hip_runtime.h>

#define LIMG 4
#define CIN 256
#define HH 128
#define WW 256
#define HW 32768          // HH*WW
#define LHW 131072        // LIMG*HW
#define CD 128
#define KP 256
#define CAP 8192
#define NSP 2
#define CPER (CIN/NSP)    // 128
#define NINF -3.402823466e38f

// ---------------- weight transpose + cnt init ----------------
__global__ void k_wtrans(const float* __restrict__ wD, float* __restrict__ wT,
                         int* __restrict__ cnt) {
  int i = blockIdx.x * 256 + threadIdx.x;
  if (i < LIMG) cnt[i] = 0;
  if (i >= CD * CIN * 9) return;
  int d = i & (CD - 1);
  int j = i >> 7;                    // c*9+tap
  wT[i] = wD[d * (CIN * 9) + j];
}

// ---------------- channel-reduced score planes ----------------
__global__ __launch_bounds__(256) void k_chanred(const float* __restrict__ feats,
                                                 const float* __restrict__ wS,
                                                 float* __restrict__ g) {
  int gp   = (blockIdx.x & 511) * 256 + threadIdx.x;  // 0..131071
  int half = blockIdx.x >> 9;                         // 0..NSP-1
  int l  = gp >> 15;
  int pi = gp & (HW - 1);
  const float* f = feats + (size_t)(l * CIN + half * CPER) * HW + pi;
  const float* w = wS + half * CPER * 9;
  float a0=0,a1=0,a2=0,a3=0,a4=0,a5=0,a6=0,a7=0,a8=0;
  #pragma unroll 4
  for (int c = 0; c < CPER; ++c) {
    float v = f[(size_t)c * HW];
    const float* wc = w + c * 9;
    a0 = fmaf(wc[0], v, a0); a1 = fmaf(wc[1], v, a1); a2 = fmaf(wc[2], v, a2);
    a3 = fmaf(wc[3], v, a3); a4 = fmaf(wc[4], v, a4); a5 = fmaf(wc[5], v, a5);
    a6 = fmaf(wc[6], v, a6); a7 = fmaf(wc[7], v, a7); a8 = fmaf(wc[8], v, a8);
  }
  float* go = g + (size_t)(half * 9) * LHW + gp;
  go[0*(size_t)LHW]=a0; go[1*(size_t)LHW]=a1; go[2*(size_t)LHW]=a2;
  go[3*(size_t)LHW]=a3; go[4*(size_t)LHW]=a4; go[5*(size_t)LHW]=a5;
  go[6*(size_t)LHW]=a6; go[7*(size_t)LHW]=a7; go[8*(size_t)LHW]=a8;
}

// ---------------- combine 9 shifted planes + bias + sigmoid ----------------
__global__ __launch_bounds__(256) void k_scores(const float* __restrict__ g,
                                                const float* __restrict__ bS,
                                                float* __restrict__ scores) {
  int gp = blockIdx.x * 256 + threadIdx.x;
  int l  = gp >> 15;
  int pi = gp & (HW - 1);
  int y = pi >> 8, x = pi & 255;
  float acc = bS[0];
  #pragma unroll
  for (int ky = 0; ky < 3; ++ky) {
    int yy = y + ky - 1;
    if (yy < 0 || yy >= HH) continue;
    #pragma unroll
    for (int kx = 0; kx < 3; ++kx) {
      int xx = x + kx - 1;
      if (xx < 0 || xx >= WW) continue;
      int tap = ky * 3 + kx;
      size_t q = (size_t)l * HW + yy * WW + xx;
      acc += g[(size_t)tap * LHW + q] + g[(size_t)(9 + tap) * LHW + q];
    }
  }
  scores[gp] = 1.0f / (1.0f + expf(-acc));
}

// ---------------- fused 9x9 maxpool + elementwise (NMS ladder) ----------------
#define PROWS 8
__global__ __launch_bounds__(256) void k_nms(int mode,
                                             const float* __restrict__ in,
                                             const float* __restrict__ scores,
                                             float* __restrict__ suppm,
                                             float* __restrict__ supps,
                                             float* __restrict__ mask) {
  __shared__ float raw[PROWS + 8][WW];
  __shared__ float rm[PROWS + 8][WW];
  int b = blockIdx.x;
  int l = b >> 4;                 // HH/PROWS = 16
  int y0 = (b & 15) * PROWS;
  int x = threadIdx.x;
  const float* inl = in + (size_t)l * HW;
  #pragma unroll
  for (int r = 0; r < PROWS + 8; ++r) {
    int yy = y0 - 4 + r;
    raw[r][x] = (yy >= 0 && yy < HH) ? inl[yy * WW + x] : NINF;
  }
  __syncthreads();
  #pragma unroll
  for (int r = 0; r < PROWS + 8; ++r) {
    float m = NINF;
    #pragma unroll
    for (int dx = -4; dx <= 4; ++dx) {
      int xx = x + dx;
      if (xx >= 0 && xx < WW) m = fmaxf(m, raw[r][xx]);
    }
    rm[r][x] = m;
  }
  __syncthreads();
  #pragma unroll
  for (int r = 0; r < PROWS; ++r) {
    float m = NINF;
    #pragma unroll
    for (int t = 0; t < 9; ++t) m = fmaxf(m, rm[r + t][x]);
    int p = l * HW + (y0 + r) * WW + x;
    float ctr = raw[r + 4][x];
    if (mode == 0) {
      mask[p] = (m == ctr) ? 1.0f : 0.0f;
    } else if (mode == 1) {
      bool s = m > 0.0f;
      suppm[p] = s ? 1.0f : 0.0f;
      supps[p] = s ? 0.0f : scores[p];
    } else {
      bool nm = (ctr == m) && (suppm[p] == 0.0f);
      mask[p] = (mask[p] != 0.0f || nm) ? 1.0f : 0.0f;
    }
  }
}

// ---------------- candidate collection ----------------
__global__ __launch_bounds__(256) void k_collect(const float* __restrict__ mask,
                                                 const float* __restrict__ scores,
                                                 int* __restrict__ cnt,
                                                 int* __restrict__ cidx,
                                                 float* __restrict__ csc) {
  int p = blockIdx.x * 256 + threadIdx.x;
  if (mask[p] != 0.0f) {
    int l = p >> 15;
    int pos = atomicAdd(&cnt[l], 1);
    if (pos < CAP) {
      cidx[l * CAP + pos] = p & (HW - 1);
      csc[l * CAP + pos]  = scores[p];
    }
  }
}

// ---------------- rank-based stable top-k via LDS-staged 64-bit keys ----------------
// key = (~bits(score)) << 32 | idx  -> ascending key order == (score desc, idx asc)
__global__ __launch_bounds__(256) void k_rank(const int* __restrict__ cnt,
                                              const int* __restrict__ cidx,
                                              const float* __restrict__ csc,
                                              int* __restrict__ sel) {
  __shared__ unsigned long long keys[CAP];   // 64 KiB
  int b = blockIdx.x;            // 32 blocks: 8 per image
  int l = b >> 3;
  int M = cnt[l]; if (M > CAP) M = CAP;
  const int* ci = cidx + l * CAP;
  const float* cs = csc + l * CAP;
  for (int j = threadIdx.x; j < M; j += 256) {
    unsigned int ks = __float_as_uint(cs[j]);   // scores > 0 -> bits monotone
    keys[j] = ((unsigned long long)(0xFFFFFFFFu - ks) << 32) | (unsigned int)ci[j];
  }
  __syncthreads();
  for (int i = (b & 7) * 256 + threadIdx.x; i < M; i += 2048) {
    unsigned long long ki = keys[i];
    int rank = 0;
    for (int j = 0; j < M; ++j)
      rank += (keys[j] < ki) ? 1 : 0;
    if (rank < KP) sel[l * KP + rank] = (int)(unsigned int)(ki & 0xFFFFFFFFu);
  }
}

// ---------------- zero-score fill when #candidates < KP ----------------
__global__ __launch_bounds__(256) void k_fill(const int* __restrict__ cnt,
                                              const float* __restrict__ mask,
                                              int* __restrict__ sel) {
  int l = blockIdx.x, tid = threadIdx.x;
  int M = cnt[l]; if (M > CAP) M = CAP;
  int Mc = (M < KP) ? M : KP;
  int need = KP - Mc;
  if (need <= 0) return;                  // uniform across block
  __shared__ int csum[256];
  const float* mk = mask + (size_t)l * HW;
  const int per = HW / 256;               // 128
  int base = tid * per;
  int c = 0;
  for (int q = 0; q < per; ++q) c += (mk[base + q] == 0.0f) ? 1 : 0;
  int inc = c;
  csum[tid] = c;
  __syncthreads();
  for (int s = 1; s < 256; s <<= 1) {
    int v = (tid >= s) ? csum[tid - s] : 0;
    __syncthreads();
    csum[tid] += v;
    __syncthreads();
  }
  int excl = csum[tid] - inc;
  if (excl < need) {
    int r = excl;
    for (int q = 0; q < per && r < need; ++q) {
      if (mk[base + q] == 0.0f) { sel[l * KP + Mc + r] = base + q; ++r; }
    }
  }
}

// ---------------- desc conv phase 1: split-K partial sums ----------------
__global__ __launch_bounds__(256) void k_desc1(const float* __restrict__ feats,
                                               const float* __restrict__ wT,
                                               const int* __restrict__ sel,
                                               float* __restrict__ pacc) {
  __shared__ float patch[4][576];     // 4 kp x (64 ch * 9 taps)
  __shared__ int kpix[4];
  int b = blockIdx.x;
  int q  = b & 3;
  int kb = (b >> 2) & 63;
  int l  = b >> 8;
  int k0 = kb * 4;
  int tid = threadIdx.x;
  if (tid < 4) kpix[tid] = sel[l * KP + k0 + tid];
  __syncthreads();
  int c0 = q * 64;
  for (int e = tid; e < 4 * 576; e += 256) {
    int kp = e / 576;
    int j  = e - kp * 576;
    int c  = j / 9;
    int tap = j - c * 9;
    int ky = tap / 3, kx = tap - ky * 3;
    int pix = kpix[kp];
    int y = pix >> 8, x = pix & 255;
    int yy = y + ky - 1, xx = x + kx - 1;
    float v = 0.0f;
    if (yy >= 0 && yy < HH && xx >= 0 && xx < WW)
      v = feats[((size_t)(l * CIN + c0 + c) * HH + yy) * WW + xx];
    patch[kp][j] = v;
  }
  __syncthreads();
  int d = tid & 127;
  int g = tid >> 7;                    // 0,1 -> kp pair (2g, 2g+1)
  const float* pa = patch[2 * g];
  const float* pb = patch[2 * g + 1];
  const float* w = wT + (size_t)(q * 576) * CD + d;
  float a0 = 0.f, a1 = 0.f;
  #pragma unroll 4
  for (int j = 0; j < 576; j += 4) {
    float4 qa = *(const float4*)&pa[j];
    float4 qb = *(const float4*)&pb[j];
    float w0 = w[(size_t)(j + 0) * CD];
    float w1 = w[(size_t)(j + 1) * CD];
    float w2 = w[(size_t)(j + 2) * CD];
    float w3 = w[(size_t)(j + 3) * CD];
    a0 = fmaf(w0, qa.x, a0); a1 = fmaf(w0, qb.x, a1);
    a0 = fmaf(w1, qa.y, a0); a1 = fmaf(w1, qb.y, a1);
    a0 = fmaf(w2, qa.z, a0); a1 = fmaf(w2, qb.z, a1);
    a0 = fmaf(w3, qa.w, a0); a1 = fmaf(w3, qb.w, a1);
  }
  size_t base = (((size_t)q * LIMG + l) * KP + k0) * CD + d;
  pacc[base + (size_t)(2 * g) * CD]     = a0;
  pacc[base + (size_t)(2 * g + 1) * CD] = a1;
}

// ---------------- desc conv phase 2: combine + bias + relu + L2 norm ----------------
__global__ __launch_bounds__(128) void k_desc2(const float* __restrict__ pacc,
                                               const float* __restrict__ bD,
                                               float* __restrict__ dkp) {
  __shared__ float ps[2];
  int b = blockIdx.x;
  int l = b >> 8, k = b & 255;
  int d = threadIdx.x;
  float s = bD[d];
  #pragma unroll
  for (int q = 0; q < 4; ++q)
    s += pacc[(((size_t)q * LIMG + l) * KP + k) * CD + d];
  float r = fmaxf(s, 0.0f);
  float v = r * r;
  #pragma unroll
  for (int sh = 32; sh > 0; sh >>= 1) v += __shfl_down(v, sh);
  if ((d & 63) == 0) ps[d >> 6] = v;
  __syncthreads();
  float n = fmaxf(sqrtf(ps[0] + ps[1]), 1e-12f);
  dkp[(size_t)(l * CD + d) * KP + k] = r / n;
}

// ---------------- cross-image attention per keypoint slot ----------------
__global__ __launch_bounds__(128) void k_attn(const float* __restrict__ dk, float* __restrict__ d2) {
  int k = blockIdx.x;
  int c = threadIdx.x;
  float q[LIMG];
  #pragma unroll
  for (int l = 0; l < LIMG; ++l) q[l] = dk[(size_t)(l * CD + c) * KP + k];
  __shared__ float qs[LIMG][CD];
  #pragma unroll
  for (int l = 0; l < LIMG; ++l) qs[l][c] = q[l];
  __syncthreads();
  __shared__ float dm[16];
  if (c < 16) {
    int n = c >> 2, m = c & 3;
    float s = 0.f;
    for (int t = 0; t < CD; ++t) s = fmaf(qs[n][t], qs[m][t], s);
    dm[c] = s * 0.08838834764831843f;     // 1/sqrt(128)
  }
  __syncthreads();
  #pragma unroll
  for (int n = 0; n < LIMG; ++n) {
    float a0 = dm[n*4+0], a1 = dm[n*4+1], a2 = dm[n*4+2], a3 = dm[n*4+3];
    float mx = fmaxf(fmaxf(a0, a1), fmaxf(a2, a3));
    float e0 = expf(a0 - mx), e1 = expf(a1 - mx), e2 = expf(a2 - mx), e3 = expf(a3 - mx);
    float inv = 1.0f / (e0 + e1 + e2 + e3);
    float msg = (e0 * q[0] + e1 * q[1] + e2 * q[2] + e3 * q[3]) * inv;
    d2[(size_t)(n * CD + c) * KP + k] = 2.0f * q[n] + msg;
  }
}

// ---------------- conv1d k=3 pad=1 + relu ----------------
__global__ __launch_bounds__(256) void k_proj(const float* __restrict__ d2, const float* __restrict__ pw,
                                              const float* __restrict__ pb, float* __restrict__ d3) {
  int b = blockIdx.x;
  int l = b >> 7, o = b & 127;
  int k = threadIdx.x;
  float acc = pb[o];
  for (int c = 0; c < CD; ++c) {
    const float* row = d2 + (size_t)(l * CD + c) * KP;
    float xm = (k > 0)      ? row[k - 1] : 0.f;
    float x0 = row[k];
    float xp = (k < KP - 1) ? row[k + 1] : 0.f;
    const float* w = pw + (size_t)(o * CD + c) * 3;
    acc = fmaf(w[0], xm, acc);
    acc = fmaf(w[1], x0, acc);
    acc = fmaf(w[2], xp, acc);
  }
  d3[(size_t)(l * CD + o) * KP + k] = fmaxf(acc, 0.f);
}

// ---------------- conv1d k=1 ----------------
__global__ __launch_bounds__(256) void k_projS(const float* __restrict__ d3, const float* __restrict__ psw,
                                               const float* __restrict__ psb, float* __restrict__ sb) {
  int b = blockIdx.x;
  int l = b >> 7, o = b & 127;
  int k = threadIdx.x;
  float acc = psb[o];
  for (int c = 0; c < CD; ++c)
    acc = fmaf(psw[o * CD + c], d3[(size_t)(l * CD + c) * KP + k], acc);
  sb[(size_t)(l * CD + o) * KP + k] = acc;
}

// ---------------- stable descending argsort per row + gather ----------------
__global__ __launch_bounds__(256) void k_sort(const float* __restrict__ sb, const float* __restrict__ d3,
                                              float* __restrict__ d4) {
  int base = blockIdx.x * KP;     // blockIdx = l*CD+o
  int j = threadIdx.x;
  __shared__ float srow[KP];
  float sj = sb[base + j];
  srow[j] = sj;
  __syncthreads();
  int rank = 0;
  for (int m = 0; m < KP; ++m) {
    float sm = srow[m];
    rank += (sm > sj || (sm == sj && m < j)) ? 1 : 0;
  }
  d4[base + rank] = d3[base + j];
}

// ---------------- final conv1d (128->3) ----------------
__global__ __launch_bounds__(256) void k_finalval(const float* __restrict__ d4, const float* __restrict__ fw,
                                                  const float* __restrict__ fb, float* __restrict__ fval) {
  int b = blockIdx.x;         // l*3+o
  int o = b % 3, l = b / 3;
  int k = threadIdx.x;
  float acc = fb[o];
  for (int c = 0; c < CD; ++c)
    acc = fmaf(fw[o * CD + c], d4[(size_t)(l * CD + c) * KP + k], acc);
  fval[b * KP + k] = acc;
}

// ---------------- min|diff| -> theta ----------------
__global__ __launch_bounds__(256) void k_theta(const float* __restrict__ fval, float* __restrict__ theta) {
  int k = threadIdx.x;
  __shared__ float sv[256];
  __shared__ float res[LIMG][3];
  for (int l = 0; l < LIMG; ++l) {
    for (int o = 0; o < 3; ++o) {
      float dv = fval[(l * 3 + o) * KP + k] - fval[o * KP + k];
      sv[k] = fabsf(dv);
      __syncthreads();
      for (int s = 128; s > 0; s >>= 1) {
        if (k < s) sv[k] = fminf(sv[k], sv[k + s]);
        __syncthreads();
      }
      if (k == 0) res[l][o] = sv[0];
      __syncthreads();
    }
  }
  if (k == 0) {
    for (int l = 0; l < LIMG; ++l) {
      float tx = res[l][0], ty = res[l][1], th = res[l][2];
      float cth = cosf(th), sth = sinf(th);
      theta[l*6+0] = cth;  theta[l*6+1] = -sth; theta[l*6+2] = tx;
      theta[l*6+3] = sth;  theta[l*6+4] = cth;  theta[l*6+5] = ty;
    }
  }
}

// ---------------- bilinear grid sample: 4 channels per thread ----------------
__global__ __launch_bounds__(256) void k_sample(const float* __restrict__ feats,
                                                const float* __restrict__ theta,
                                                float* __restrict__ out) {
  int b = blockIdx.x;
  int pb = b & 127;
  int cg = (b >> 7) & 63;
  int l  = b >> 13;
  int pi = pb * 256 + threadIdx.x;
  int x = pi & 255, y = pi >> 8;
  const float* t = theta + l * 6;
  float X = (x + 0.5f) * (2.0f / WW) - 1.0f;
  float Y = (y + 0.5f) * (2.0f / HH) - 1.0f;
  float gx = t[0] * X + t[1] * Y + t[2];
  float gy = t[3] * X + t[4] * Y + t[5];
  float ix = ((gx + 1.0f) * WW - 1.0f) * 0.5f;
  float iy = ((gy + 1.0f) * HH - 1.0f) * 0.5f;
  float x0 = floorf(ix), y0 = floorf(iy);
  float x1 = x0 + 1.0f,  y1 = y0 + 1.0f;
  float wa = (x1 - ix) * (y1 - iy);
  float wb = (ix - x0) * (y1 - iy);
  float wc = (x1 - ix) * (iy - y0);
  float wd = (ix - x0) * (iy - y0);
  bool vx0 = (x0 >= 0.f) && (x0 <= (float)(WW-1));
  bool vx1 = (x1 >= 0.f) && (x1 <= (float)(WW-1));
  bool vy0 = (y0 >= 0.f) && (y0 <= (float)(HH-1));
  bool vy1 = (y1 >= 0.f) && (y1 <= (float)(HH-1));
  wa = (vx0 && vy0) ? wa : 0.f;
  wb = (vx1 && vy0) ? wb : 0.f;
  wc = (vx0 && vy1) ? wc : 0.f;
  wd = (vx1 && vy1) ? wd : 0.f;
  int xc0 = (int)fminf(fmaxf(x0, 0.f), (float)(WW-1));
  int xc1 = (int)fminf(fmaxf(x1, 0.f), (float)(WW-1));
  int yc0 = (int)fminf(fmaxf(y0, 0.f), (float)(HH-1));
  int yc1 = (int)fminf(fmaxf(y1, 0.f), (float)(HH-1));
  int o00 = yc0 * WW + xc0;
  int o10 = yc0 * WW + xc1;
  int o01 = yc1 * WW + xc0;
  int o11 = yc1 * WW + xc1;
  const float* img = feats + (size_t)(l * CIN + cg * 4) * HW;
  float* op = out + (size_t)(l * CIN + cg * 4) * HW + pi;
  #pragma unroll
  for (int i = 0; i < 4; ++i) {
    const float* im = img + (size_t)i * HW;
    float acc = im[o00] * wa + im[o10] * wb + im[o01] * wc + im[o11] * wd;
    op[(size_t)i * HW] = acc;
  }
}

extern "C" void kernel_launch(void* const* d_in, const int* in_sizes, int n_in,
                              void* d_out, int out_size, void* d_ws, size_t ws_size,
                              hipStream_t stream) {
  const float* feats = (const float*)d_in[0];
  const float* wS    = (const float*)d_in[1];
  const float* bS    = (const float*)d_in[2];
  const float* wD    = (const float*)d_in[3];
  const float* bD    = (const float*)d_in[4];
  const float* pw    = (const float*)d_in[5];
  const float* pb    = (const float*)d_in[6];
  const float* psw   = (const float*)d_in[7];
  const float* psb   = (const float*)d_in[8];
  const float* fw    = (const float*)d_in[9];
  const float* fb    = (const float*)d_in[10];
  float* out = (float*)d_out;

  char* base = (char*)d_ws;
  size_t off = 0;
  auto alloc = [&](size_t bytes) -> void* {
    void* p = base + off;
    off = (off + bytes + 255) & ~(size_t)255;
    return p;
  };
  float* g      = (float*)alloc((size_t)NSP * 9 * LHW * sizeof(float));
  float* scores = (float*)alloc((size_t)LHW * 4);
  float* mask   = (float*)alloc((size_t)LHW * 4);
  float* suppm  = (float*)alloc((size_t)LHW * 4);
  float* supps  = (float*)alloc((size_t)LHW * 4);
  float* dkp    = (float*)alloc((size_t)LHW * 4);
  float* d2     = (float*)alloc((size_t)LHW * 4);
  float* d3     = (float*)alloc((size_t)LHW * 4);
  float* sb     = (float*)alloc((size_t)LHW * 4);
  float* d4     = (float*)alloc((size_t)LHW * 4);
  float* wT     = (float*)alloc((size_t)CIN * 9 * CD * 4);
  float* pacc   = (float*)alloc((size_t)4 * LIMG * KP * CD * 4);
  float* fval   = (float*)alloc((size_t)12 * KP * 4);
  float* theta  = (float*)alloc(24 * 4);
  float* csc    = (float*)alloc((size_t)LIMG * CAP * 4);
  int*   cidx   = (int*)  alloc((size_t)LIMG * CAP * 4);
  int*   cnt    = (int*)  alloc(64);
  int*   sel    = (int*)  alloc((size_t)LIMG * KP * 4);

  k_wtrans<<<(CD * CIN * 9 + 255) / 256, 256, 0, stream>>>(wD, wT, cnt);
  k_chanred<<<NSP * 512, 256, 0, stream>>>(feats, wS, g);
  k_scores<<<512, 256, 0, stream>>>(g, bS, scores);
  k_nms<<<64, 256, 0, stream>>>(0, scores, scores, suppm, supps, mask);
  for (int it = 0; it < 2; ++it) {
    k_nms<<<64, 256, 0, stream>>>(1, mask,  scores, suppm, supps, mask);
    k_nms<<<64, 256, 0, stream>>>(2, supps, scores, suppm, supps, mask);
  }
  k_collect<<<512, 256, 0, stream>>>(mask, scores, cnt, cidx, csc);
  k_rank<<<32, 256, 0, stream>>>(cnt, cidx, csc, sel);
  k_fill<<<LIMG, 256, 0, stream>>>(cnt, mask, sel);
  k_desc1<<<1024, 256, 0, stream>>>(feats, wT, sel, pacc);
  k_desc2<<<1024, 128, 0, stream>>>(pacc, bD, dkp);
  k_attn<<<256, 128, 0, stream>>>(dkp, d2);
  k_proj<<<512, 256, 0, stream>>>(d2, pw, pb, d3);
  k_projS<<<512, 256, 0, stream>>>(d3, psw, psb, sb);
  k_sort<<<512, 256, 0, stream>>>(sb, d3, d4);
  k_finalval<<<12, 256, 0, stream>>>(d4, fw, fb, fval);
  k_theta<<<1, 256, 0, stream>>>(fval, theta);
  k_sample<<<32768, 256, 0, stream>>>(feats, theta, out);
}